// Round 2
// baseline (2920.157 us; speedup 1.0000x reference)
//
#include <hip/hip_runtime.h>
#include <hip/hip_bf16.h>
#include <stdint.h>

typedef __hip_bfloat16 bf16;
typedef __attribute__((ext_vector_type(8))) short short8;   // 8 bf16 in 4 VGPRs
typedef __attribute__((ext_vector_type(4))) float f32x4;

#define BB 256
#define NN1 10240
#define EE1 81920
#define NN3 25600
#define EE3 819200

// ---------------------------------------------------------------- helpers
__device__ __forceinline__ void load16_g2l(const void* g, void* l) {
  __builtin_amdgcn_global_load_lds(
      (const __attribute__((address_space(1))) void*)(uintptr_t)g,
      (__attribute__((address_space(3))) void*)(uintptr_t)l, 16, 0, 0);
}

__device__ __forceinline__ void atomicMaxF(float* a, float v) {
  if (v >= 0.f) atomicMax((int*)a, __float_as_int(v));
  else          atomicMin((unsigned int*)a, __float_as_uint(v));
}

// ---------------------------------------------------------------- casts
__global__ void cast_pad_bf(const float* __restrict__ in, bf16* __restrict__ out,
                            int M, int K, int Kp) {
  int i = blockIdx.x * blockDim.x + threadIdx.x;
  if (i >= M * Kp) return;
  int r = i / Kp, c = i - r * Kp;
  out[i] = __float2bfloat16(c < K ? in[(size_t)r * K + c] : 0.f);
}

// out[Np][Kp] = in[K][N]^T  (pad with zeros)
__global__ void transpose_cast_bf(const float* __restrict__ in, bf16* __restrict__ out,
                                  int K, int N, int Kp, int Np) {
  int i = blockIdx.x * blockDim.x + threadIdx.x;
  if (i >= Np * Kp) return;
  int n = i / Kp, k = i - n * Kp;
  float v = (k < K && n < N) ? in[(size_t)k * N + n] : 0.f;
  out[i] = __float2bfloat16(v);
}

__global__ void cast_bf(const float* __restrict__ in, bf16* __restrict__ out, int n) {
  int i = blockIdx.x * blockDim.x + threadIdx.x;
  if (i < n) out[i] = __float2bfloat16(in[i]);
}

// ---------------------------------------------------------------- MFMA GEMM
// C[M,N] = act(A[M,K]bf16 @ Bt[N,K]bf16^T + bias).  128x128 tile, BK=32,
// 4 waves (2x2), each wave 64x64 = 4x4 16x16x32 fragments. Single-buffer LDS,
// global_load_lds staging (m97 structure). M%128==0, N%128==0, K%32==0.
template<int RELU, int OUT_F32, int CONCAT_LI>
__global__ __launch_bounds__(256) void gemm_mfma(
    const bf16* __restrict__ A, const bf16* __restrict__ Bt,
    const float* __restrict__ bias, void* __restrict__ Cout,
    const float* __restrict__ li, int M, int N, int K)
{
  __shared__ __align__(16) unsigned short sA[128 * 32];
  __shared__ __align__(16) unsigned short sB[128 * 32];
  const int nBN = N >> 7;
  const int bm = blockIdx.x / nBN, bn = blockIdx.x - bm * nBN;
  const size_t m0 = (size_t)bm << 7, n0 = (size_t)bn << 7;
  const int t = threadIdx.x;
  const int lane = t & 63, wave = t >> 6;
  const int wr = wave >> 1, wc = wave & 1;
  const int srow = t >> 2;            // 0..63 staging row
  const int scol = (t & 3) << 3;      // bf16 col offset (8-elem chunks)
  const bf16* Ab = A + (m0 + srow) * (size_t)K + scol;
  const bf16* Bb = Bt + (n0 + srow) * (size_t)K + scol;
  unsigned short* sAd = &sA[srow * 32 + scol];
  unsigned short* sBd = &sB[srow * 32 + scol];
  const int lr = lane & 15;
  const int lk = (lane >> 4) << 3;

  f32x4 zero = {0.f, 0.f, 0.f, 0.f};
  f32x4 acc[4][4];
#pragma unroll
  for (int i = 0; i < 4; i++)
#pragma unroll
    for (int j = 0; j < 4; j++) acc[i][j] = zero;

  for (int k0 = 0; k0 < K; k0 += 32) {
    load16_g2l(Ab + k0, sAd);
    load16_g2l(Ab + (size_t)64 * K + k0, sAd + 64 * 32);
    load16_g2l(Bb + k0, sBd);
    load16_g2l(Bb + (size_t)64 * K + k0, sBd + 64 * 32);
    __syncthreads();   // drains vmcnt (global_load_lds) per compiler semantics
    short8 af[4], bv[4];
#pragma unroll
    for (int i = 0; i < 4; i++) af[i] = *(const short8*)&sA[(wr * 64 + i * 16 + lr) * 32 + lk];
#pragma unroll
    for (int i = 0; i < 4; i++) bv[i] = *(const short8*)&sB[(wc * 64 + i * 16 + lr) * 32 + lk];
#pragma unroll
    for (int i = 0; i < 4; i++)
#pragma unroll
      for (int j = 0; j < 4; j++)
        acc[i][j] = __builtin_amdgcn_mfma_f32_16x16x32_bf16(af[i], bv[j], acc[i][j], 0, 0, 0);
    __syncthreads();
  }

  // epilogue: C row=(lane>>4)*4+v, col=lane&15 per fragment (m89/m91 layout)
  const int crow = wr * 64, ccol = wc * 64;
#pragma unroll
  for (int i = 0; i < 4; i++) {
#pragma unroll
    for (int j = 0; j < 4; j++) {
      const size_t gc = n0 + ccol + j * 16 + lr;
      const bool isLi = CONCAT_LI && (gc == (size_t)(N - 1));
      float bvf = (!isLi && bias) ? bias[gc] : 0.f;
#pragma unroll
      for (int v = 0; v < 4; v++) {
        const size_t gr = m0 + crow + i * 16 + (lane >> 4) * 4 + v;
        float val = acc[i][j][v] + bvf;
        if (RELU) val = fmaxf(val, 0.f);
        if (isLi) val = li[gr];                      // concat ami_dis_li (no relu/bias)
        if (OUT_F32) ((float*)Cout)[gr * N + gc] = val;
        else ((bf16*)Cout)[gr * N + gc] = __float2bfloat16(val);
      }
    }
  }
}

// ---------------------------------------------------------------- SIMT GEMM (small)
template<int RELU, int BN>
__global__ void gemm_simt(const float* __restrict__ A, const float* __restrict__ W,
                          const float* __restrict__ bias,
                          const float* __restrict__ bng, const float* __restrict__ bnb,
                          const float* __restrict__ bnm, const float* __restrict__ bnv,
                          float* __restrict__ C, int M, int N, int K)
{
  int idx = blockIdx.x * blockDim.x + threadIdx.x;
  if (idx >= M * N) return;
  int m = idx / N, n = idx - m * N;
  const float* a = A + (size_t)m * K;
  float acc = bias[n];
  for (int k = 0; k < K; k++) acc = fmaf(a[k], W[(size_t)k * N + n], acc);
  if (BN) acc = (acc - bnm[n]) * rsqrtf(bnv[n] + 1e-5f) * bng[n] + bnb[n];
  if (RELU) acc = fmaxf(acc, 0.f);
  C[idx] = acc;
}

// ---------------------------------------------------------------- GCN pieces
__global__ void deg_kernel(const int* __restrict__ col, const float* __restrict__ w,
                           float* __restrict__ deg, int E) {
  int e = blockIdx.x * blockDim.x + threadIdx.x;
  if (e < E) atomicAdd(&deg[col[e]], w[e]);
}

__global__ void dinv_kernel(const float* __restrict__ deg, float* __restrict__ dinv, int n) {
  int i = blockIdx.x * blockDim.x + threadIdx.x;
  if (i >= n) return;
  float d = deg[i] + 1.0f;                       // + self-loop weight 1
  dinv[i] = d > 0.f ? rsqrtf(fmaxf(d, 1e-12f)) : 0.f;
}

__global__ void gcn_scatter(const int* __restrict__ row, const int* __restrict__ col,
                            const float* __restrict__ w, const float* __restrict__ dinv,
                            const float* __restrict__ h, float* __restrict__ s, int E) {
  int gi = blockIdx.x * blockDim.x + threadIdx.x;
  if (gi >= E * 128) return;
  int e = gi >> 7, d = gi & 127;
  int r = row[e], c = col[e];
  float nrm = dinv[r] * w[e] * dinv[c];
  atomicAdd(&s[(size_t)c * 128 + d], h[(size_t)r * 128 + d] * nrm);
}

// a = relu(s + h*dinv^2 + bias); pool[batch] += a   (self-loop folded in here)
__global__ void gcn_finish(const float* __restrict__ s, const float* __restrict__ h,
                           const float* __restrict__ dinv, const float* __restrict__ bias,
                           float* __restrict__ a, float* __restrict__ pool,
                           const int* __restrict__ batch, int n) {
  int gi = blockIdx.x * blockDim.x + threadIdx.x;
  if (gi >= n * 128) return;
  int i = gi >> 7, d = gi & 127;
  float di = dinv[i];
  float val = fmaxf(s[gi] + h[gi] * di * di + bias[d], 0.f);
  a[gi] = val;
  atomicAdd(&pool[(size_t)batch[i] * 128 + d], val);
}

// ---------------------------------------------------------------- GAT pieces
__global__ void gat_uv(const float* __restrict__ h, const float* __restrict__ as,
                       const float* __restrict__ ad, float* __restrict__ u,
                       float* __restrict__ v, int n) {
  int wave = threadIdx.x >> 6, lane = threadIdx.x & 63;
  int row = blockIdx.x * 4 + wave;
  if (row >= n) return;
  const float* hr = h + (size_t)row * 128;
  float su = 0.f, sv = 0.f;
  for (int d = lane; d < 128; d += 64) { float x = hr[d]; su += x * as[d]; sv += x * ad[d]; }
  for (int off = 32; off; off >>= 1) { su += __shfl_down(su, off); sv += __shfl_down(sv, off); }
  if (lane == 0) { u[row] = su; v[row] = sv; }
}

__global__ void gat_logit(const int* __restrict__ src, const int* __restrict__ dst,
                          const float* __restrict__ u, const float* __restrict__ v,
                          float* __restrict__ elog, float* __restrict__ marr, int E, int Etot) {
  int e = blockIdx.x * blockDim.x + threadIdx.x;
  if (e >= Etot) return;
  int s, t;
  if (e < E) { s = src[e]; t = dst[e]; } else { s = t = e - E; }
  float lg = u[s] + v[t];
  lg = lg >= 0.f ? lg : 0.2f * lg;                // leaky_relu(0.2)
  elog[e] = lg;
  atomicMaxF(&marr[t], lg);
}

__global__ void gat_exp(const int* __restrict__ dst, float* __restrict__ elog,
                        const float* __restrict__ marr, float* __restrict__ sarr,
                        int E, int Etot) {
  int e = blockIdx.x * blockDim.x + threadIdx.x;
  if (e >= Etot) return;
  int t = e < E ? dst[e] : e - E;
  float ee = expf(elog[e] - marr[t]);
  elog[e] = ee;
  atomicAdd(&sarr[t], ee);
}

__global__ void gat_scatter(const int* __restrict__ src, const int* __restrict__ dst,
                            const float* __restrict__ elog, const float* __restrict__ sarr,
                            const float* __restrict__ h, float* __restrict__ out, int E, int Etot) {
  int gi = blockIdx.x * blockDim.x + threadIdx.x;
  if (gi >= Etot * 128) return;
  int e = gi >> 7, d = gi & 127;
  int s, t;
  if (e < E) { s = src[e]; t = dst[e]; } else { s = t = e - E; }
  float alpha = elog[e] / sarr[t];
  atomicAdd(&out[(size_t)t * 128 + d], h[(size_t)s * 128 + d] * alpha);
}

__global__ void gat_finish(float* __restrict__ x, const float* __restrict__ bias,
                           float* __restrict__ pool, const int* __restrict__ batch, int n) {
  int gi = blockIdx.x * blockDim.x + threadIdx.x;
  if (gi >= n * 128) return;
  int i = gi >> 7, d = gi & 127;
  float val = fmaxf(x[gi] + bias[d], 0.f);
  x[gi] = val;
  atomicAdd(&pool[(size_t)batch[i] * 128 + d], val);
}

// ---------------------------------------------------------------- elementwise
__global__ void cnt_kernel(const int* __restrict__ batch, float* __restrict__ cnt, int n) {
  int i = blockIdx.x * blockDim.x + threadIdx.x;
  if (i < n) atomicAdd(&cnt[batch[i]], 1.0f);
}

__global__ void pool_div(const float* __restrict__ pool, const float* __restrict__ cnt,
                         float* __restrict__ out, int n) {
  int i = blockIdx.x * blockDim.x + threadIdx.x;
  if (i < n) out[i] = pool[i] / fmaxf(cnt[i >> 7], 1.f);
}

__global__ void fill_val(float* __restrict__ p, float v, int n) {
  int i = blockIdx.x * blockDim.x + threadIdx.x;
  if (i < n) p[i] = v;
}

__global__ void fill_t(float* __restrict__ t, const float* __restrict__ vn, int n) {
  int i = blockIdx.x * blockDim.x + threadIdx.x;
  if (i < n) t[i] = vn[i & 127];
}

__global__ void scatter_t(const float* __restrict__ x, const int* __restrict__ batch,
                          float* __restrict__ t, int n) {
  int gi = blockIdx.x * blockDim.x + threadIdx.x;
  if (gi >= n) return;
  int i = gi >> 7, d = gi & 127;
  atomicAdd(&t[(size_t)batch[i] * 128 + d], x[gi]);
}

__global__ void add_vn(const float* __restrict__ h, const float* __restrict__ vn,
                       float* __restrict__ out, int n) {
  int i = blockIdx.x * blockDim.x + threadIdx.x;
  if (i < n) out[i] = h[i] + 0.2f * vn[i & 127];
}

__global__ void add_drug(const float* __restrict__ x11, const float* __restrict__ dr,
                         const int* __restrict__ batch, float* __restrict__ out, int n) {
  int gi = blockIdx.x * blockDim.x + threadIdx.x;
  if (gi >= n) return;
  int i = gi >> 7, d = gi & 127;
  out[gi] = x11[gi] + 0.2f * dr[(size_t)batch[i] * 128 + d];
}

__global__ void concat_k(const float* __restrict__ xg, const float* __restrict__ ami,
                         float* __restrict__ z, int n) {
  int i = blockIdx.x * blockDim.x + threadIdx.x;
  if (i >= n) return;
  int b = i >> 8, d = i & 255;
  z[i] = d < 128 ? xg[(b << 7) + d] : ami[(b << 7) + d - 128];
}

__global__ void relu_k(const float* __restrict__ in, float* __restrict__ out, int n) {
  int i = blockIdx.x * blockDim.x + threadIdx.x;
  if (i < n) out[i] = fmaxf(in[i], 0.f);
}

// ---------------------------------------------------------------- launch
static inline int cdiv(int a, int b) { return (a + b - 1) / b; }

extern "C" void kernel_launch(void* const* d_in, const int* in_sizes, int n_in,
                              void* d_out, int out_size, void* d_ws, size_t ws_size,
                              hipStream_t stream)
{
  const float* x1      = (const float*)d_in[0];
  const float* x3      = (const float*)d_in[1];
  const float* ami_dis = (const float*)d_in[2];
  const float* ami_li  = (const float*)d_in[3];
  const float* fc00_w = (const float*)d_in[4];  const float* fc00_b = (const float*)d_in[5];
  const float* fc01_w = (const float*)d_in[6];  const float* fc01_b = (const float*)d_in[7];
  const float* fc02_w = (const float*)d_in[8];  const float* fc02_b = (const float*)d_in[9];
  const float* w1 = (const float*)d_in[10];     const float* b1 = (const float*)d_in[11];
  const float* w2 = (const float*)d_in[12];     const float* b2 = (const float*)d_in[13];
  const float* fc03_w = (const float*)d_in[14]; const float* fc03_b = (const float*)d_in[15];
  const float* gat_W  = (const float*)d_in[16]; const float* gat_as = (const float*)d_in[17];
  const float* gat_ad = (const float*)d_in[18]; const float* gat_bias = (const float*)d_in[19];
  const float* vn_emb = (const float*)d_in[20];
  const float* vl1_w = (const float*)d_in[21];  const float* vl1_b = (const float*)d_in[22];
  const float* bn1_g = (const float*)d_in[23];  const float* bn1_b = (const float*)d_in[24];
  const float* bn1_m = (const float*)d_in[25];  const float* bn1_v = (const float*)d_in[26];
  const float* vl2_w = (const float*)d_in[27];  const float* vl2_b = (const float*)d_in[28];
  const float* bn2_g = (const float*)d_in[29];  const float* bn2_b = (const float*)d_in[30];
  const float* bn2_m = (const float*)d_in[31];  const float* bn2_v = (const float*)d_in[32];
  const float* gcn_W = (const float*)d_in[33];  const float* gcn_b = (const float*)d_in[34];
  const float* fc1_w = (const float*)d_in[35];  const float* fc1_b = (const float*)d_in[36];
  const float* fc2_w = (const float*)d_in[37];  const float* fc2_b = (const float*)d_in[38];
  const float* fc3_w = (const float*)d_in[39];  const float* fc3_b = (const float*)d_in[40];
  const float* out_w = (const float*)d_in[41];  const float* out_b = (const float*)d_in[42];
  const int* drug_ei   = (const int*)d_in[43];
  const int* ami_ei    = (const int*)d_in[44];
  const int* batch1    = (const int*)d_in[45];
  const int* ami_batch = (const int*)d_in[46];

  char* ws = (char*)d_ws;
  // ---- small persistent arena (~8 MB)
  bf16*  Bt0   = (bf16*)(ws + 0);          // 1024x1920
  bf16*  Bt1   = (bf16*)(ws + 3932160);    // 512x1024
  bf16*  Bt2   = (bf16*)(ws + 4980736);    // 128x512 (row127=0)
  bf16*  BtGCN = (bf16*)(ws + 5111808);    // 3x128x128
  bf16*  BtGAT = (bf16*)(ws + 5210112);    // 3x128x128
  float* deg   = (float*)(ws + 5308416);
  float* dinv  = (float*)(ws + 5410816);
  float* pool_ami  = (float*)(ws + 5513216);
  float* pool_drug = (float*)(ws + 5644288);
  float* cnt_ami   = (float*)(ws + 5775360);
  float* cnt_drug  = (float*)(ws + 5776384);
  float* amivec    = (float*)(ws + 5777408);
  float* xg        = (float*)(ws + 5908480);
  float* uarr  = (float*)(ws + 6039552);
  float* varr  = (float*)(ws + 6080512);
  float* marr  = (float*)(ws + 6121472);
  float* sarr  = (float*)(ws + 6162432);
  float* elog  = (float*)(ws + 6203392);   // 92160
  float* tbuf  = (float*)(ws + 6572032);   // 256x128
  float* t2buf = (float*)(ws + 6703104);   // 256x256
  float* drugv = (float*)(ws + 6965248);   // 256x128
  float* zbuf  = (float*)(ws + 7096320);   // 256x256
  float* z2buf = (float*)(ws + 7358464);   // 256x512
  float* z3buf = (float*)(ws + 7882752);   // 256x256
  float* z4buf = (float*)(ws + 8144896);   // 256x128
  // ---- arena A (98.3 MB, aliased across phases)
  const size_t AA = 8388608;
  bf16*  A3bf = (bf16*)(ws + AA);                    // 25600x1920 (GEMM1 input)
  bf16*  a2bf = (bf16*)(ws + AA);                    // 25600x512  (after GEMM1)
  float* aG   = (float*)(ws + AA + 26214400);        // 25600x128
  bf16*  abf  = (bf16*) (ws + AA + 39321600);        // 25600x128 bf16
  float* hG   = (float*)(ws + AA + 45875200);        // 25600x128
  float* sG   = (float*)(ws + AA + 58982400);        // 25600x128
  // drug phase reuse of arena A (ami arrays dead by then)
  float* h1    = (float*)(ws + AA + 0);              // 10240x128
  float* hd2   = (float*)(ws + AA + 5242880);        // 10240x64
  float* h3    = (float*)(ws + AA + 7864320);        // 10240x128
  float* xdrug = (float*)(ws + AA + 13107200);
  float* x11   = (float*)(ws + AA + 18350080);
  float* x2b   = (float*)(ws + AA + 23592960);
  float* x12   = (float*)(ws + AA + 28835840);
  float* x13   = (float*)(ws + AA + 34078720);
  bf16*  xbf   = (bf16*) (ws + AA + 39321600);
  float* hgat  = (float*)(ws + AA + 41943040);
  // ---- arena B
  const size_t ABo = AA + 98304000;
  bf16*  a1bf = (bf16*)(ws + ABo);                   // 25600x1024  (total ~159.1 MB)

  // ================= prep: weight transposes + x3 cast =================
  transpose_cast_bf<<<cdiv(1024 * 1920, 256), 256, 0, stream>>>(fc00_w, Bt0, 1900, 1024, 1920, 1024);
  transpose_cast_bf<<<cdiv(512 * 1024, 256), 256, 0, stream>>>(fc01_w, Bt1, 1024, 512, 1024, 512);
  transpose_cast_bf<<<cdiv(128 * 512, 256), 256, 0, stream>>>(fc02_w, Bt2, 512, 127, 512, 128);
  for (int l = 0; l < 3; l++) {
    transpose_cast_bf<<<cdiv(16384, 256), 256, 0, stream>>>(gcn_W + l * 16384, BtGCN + l * 16384, 128, 128, 128, 128);
    transpose_cast_bf<<<cdiv(16384, 256), 256, 0, stream>>>(gat_W + l * 16384, BtGAT + l * 16384, 128, 128, 128, 128);
  }
  cast_pad_bf<<<cdiv(25600 * 1920, 256), 256, 0, stream>>>(x3, A3bf, 25600, 1900, 1920);

  // ================= ami branch: MLP (bf16 MFMA) =================
  gemm_mfma<1, 0, 0><<<200 * 8, 256, 0, stream>>>(A3bf, Bt0, fc00_b, a1bf, nullptr, 25600, 1024, 1920);
  gemm_mfma<1, 0, 0><<<200 * 4, 256, 0, stream>>>(a1bf, Bt1, fc01_b, a2bf, nullptr, 25600, 512, 1024);
  gemm_mfma<1, 1, 1><<<200 * 1, 256, 0, stream>>>(a2bf, Bt2, fc02_b, aG, ami_li, 25600, 128, 512);

  // ================= GCN prep =================
  hipMemsetAsync(deg, 0, 102400, stream);
  hipMemsetAsync(pool_ami, 0, 131072, stream);
  hipMemsetAsync(pool_drug, 0, 131072, stream);
  hipMemsetAsync(cnt_ami, 0, 1024, stream);
  hipMemsetAsync(cnt_drug, 0, 1024, stream);
  deg_kernel<<<cdiv(EE3, 256), 256, 0, stream>>>(ami_ei + EE3, ami_dis, deg, EE3);
  dinv_kernel<<<cdiv(NN3, 256), 256, 0, stream>>>(deg, dinv, NN3);
  cnt_kernel<<<cdiv(NN3, 256), 256, 0, stream>>>(ami_batch, cnt_ami, NN3);
  cnt_kernel<<<cdiv(NN1, 256), 256, 0, stream>>>(batch1, cnt_drug, NN1);

  // ================= 3x GCN =================
  for (int l = 0; l < 3; l++) {
    cast_bf<<<cdiv(NN3 * 128, 256), 256, 0, stream>>>(aG, abf, NN3 * 128);
    gemm_mfma<0, 1, 0><<<200, 256, 0, stream>>>(abf, BtGCN + l * 16384, nullptr, hG, nullptr, NN3, 128, 128);
    hipMemsetAsync(sG, 0, (size_t)NN3 * 128 * 4, stream);
    gcn_scatter<<<cdiv(EE3 * 128, 256), 256, 0, stream>>>(ami_ei, ami_ei + EE3, ami_dis, dinv, hG, sG, EE3);
    gcn_finish<<<cdiv(NN3 * 128, 256), 256, 0, stream>>>(sG, hG, dinv, gcn_b + l * 128, aG, pool_ami, ami_batch, NN3);
  }
  pool_div<<<cdiv(BB * 128, 256), 256, 0, stream>>>(pool_ami, cnt_ami, amivec, BB * 128);

  // ================= drug branch: MLP =================
  gemm_simt<1, 0><<<cdiv(NN1 * 128, 256), 256, 0, stream>>>(x1, w1, b1, nullptr, nullptr, nullptr, nullptr, h1, NN1, 128, 52);
  gemm_simt<1, 0><<<cdiv(NN1 * 64, 256), 256, 0, stream>>>(h1, w2, b2, nullptr, nullptr, nullptr, nullptr, hd2, NN1, 64, 128);
  gemm_simt<0, 0><<<cdiv(NN1 * 128, 256), 256, 0, stream>>>(hd2, fc03_w, fc03_b, nullptr, nullptr, nullptr, nullptr, h3, NN1, 128, 64);
  add_vn<<<cdiv(NN1 * 128, 256), 256, 0, stream>>>(h3, vn_emb, xdrug, NN1 * 128);

  const int Etot = EE1 + NN1;
  auto gat_layer = [&](int l, const float* xin, float* xout) {
    cast_bf<<<cdiv(NN1 * 128, 256), 256, 0, stream>>>(xin, xbf, NN1 * 128);
    gemm_mfma<0, 1, 0><<<80, 256, 0, stream>>>(xbf, BtGAT + l * 16384, nullptr, hgat, nullptr, NN1, 128, 128);
    gat_uv<<<cdiv(NN1, 4), 256, 0, stream>>>(hgat, gat_as + l * 128, gat_ad + l * 128, uarr, varr, NN1);
    fill_val<<<cdiv(NN1, 256), 256, 0, stream>>>(marr, -__builtin_inff(), NN1);
    hipMemsetAsync(sarr, 0, NN1 * 4, stream);
    gat_logit<<<cdiv(Etot, 256), 256, 0, stream>>>(drug_ei, drug_ei + EE1, uarr, varr, elog, marr, EE1, Etot);
    gat_exp<<<cdiv(Etot, 256), 256, 0, stream>>>(drug_ei + EE1, elog, marr, sarr, EE1, Etot);
    hipMemsetAsync(xout, 0, (size_t)NN1 * 128 * 4, stream);
    gat_scatter<<<cdiv(Etot * 128, 256), 256, 0, stream>>>(drug_ei, drug_ei + EE1, elog, sarr, hgat, xout, EE1, Etot);
    gat_finish<<<cdiv(NN1 * 128, 256), 256, 0, stream>>>(xout, gat_bias + l * 128, pool_drug, batch1, NN1);
  };

  gat_layer(0, xdrug, x11);

  // virtual-node update
  fill_t<<<cdiv(BB * 128, 256), 256, 0, stream>>>(tbuf, vn_emb, BB * 128);
  scatter_t<<<cdiv(NN1 * 128, 256), 256, 0, stream>>>(x11, batch1, tbuf, NN1 * 128);
  gemm_simt<1, 1><<<cdiv(BB * 256, 256), 256, 0, stream>>>(tbuf, vl1_w, vl1_b, bn1_g, bn1_b, bn1_m, bn1_v, t2buf, BB, 256, 128);
  gemm_simt<1, 1><<<cdiv(BB * 128, 256), 256, 0, stream>>>(t2buf, vl2_w, vl2_b, bn2_g, bn2_b, bn2_m, bn2_v, drugv, BB, 128, 256);
  add_drug<<<cdiv(NN1 * 128, 256), 256, 0, stream>>>(x11, drugv, batch1, x2b, NN1 * 128);

  gat_layer(1, x2b, x12);
  gat_layer(2, x2b, x13);
  pool_div<<<cdiv(BB * 128, 256), 256, 0, stream>>>(pool_drug, cnt_drug, xg, BB * 128);

  // ================= fused head =================
  concat_k<<<cdiv(BB * 256, 256), 256, 0, stream>>>(xg, amivec, zbuf, BB * 256);
  float* h2out = (float*)d_out + 256;     // output tuple: (out[256], h2[256x512])
  gemm_simt<0, 0><<<cdiv(BB * 512, 256), 256, 0, stream>>>(zbuf, fc1_w, fc1_b, nullptr, nullptr, nullptr, nullptr, h2out, BB, 512, 256);
  relu_k<<<cdiv(BB * 512, 256), 256, 0, stream>>>(h2out, z2buf, BB * 512);
  gemm_simt<1, 0><<<cdiv(BB * 256, 256), 256, 0, stream>>>(z2buf, fc2_w, fc2_b, nullptr, nullptr, nullptr, nullptr, z3buf, BB, 256, 512);
  gemm_simt<1, 0><<<cdiv(BB * 128, 256), 256, 0, stream>>>(z3buf, fc3_w, fc3_b, nullptr, nullptr, nullptr, nullptr, z4buf, BB, 128, 256);
  gemm_simt<0, 0><<<1, 256, 0, stream>>>(z4buf, out_w, out_b, nullptr, nullptr, nullptr, nullptr, (float*)d_out, BB, 1, 128);
}

// Round 3
// 2030.044 us; speedup vs baseline: 1.4385x; 1.4385x over previous
//
#include <hip/hip_runtime.h>
#include <hip/hip_bf16.h>
#include <stdint.h>

typedef __hip_bfloat16 bf16;
typedef __attribute__((ext_vector_type(8))) short short8;   // 8 bf16 in 4 VGPRs
typedef __attribute__((ext_vector_type(4))) float f32x4;

#define BB 256
#define NN1 10240
#define EE1 81920
#define NN3 25600
#define EE3 819200

// ---------------------------------------------------------------- helpers
__device__ __forceinline__ void load16_g2l(const void* g, void* l) {
  __builtin_amdgcn_global_load_lds(
      (const __attribute__((address_space(1))) void*)(uintptr_t)g,
      (__attribute__((address_space(3))) void*)(uintptr_t)l, 16, 0, 0);
}

__device__ __forceinline__ unsigned short f2bfbits(float v) {
  bf16 t = __float2bfloat16(v);
  union { bf16 b; unsigned short u; } x; x.b = t; return x.u;
}

// ---------------------------------------------------------------- casts
// vectorized cast+pad: 8 bf16 outputs per thread
__global__ void cast_pad8(const float* __restrict__ in, bf16* __restrict__ out,
                          int M, int K, int Kp) {
  int nch = Kp >> 3;
  int i = blockIdx.x * blockDim.x + threadIdx.x;
  if (i >= M * nch) return;
  int r = i / nch, c8 = (i - r * nch) << 3;
  const float* s = in + (size_t)r * K + c8;
  short8 o;
  if (c8 + 8 <= K) {
    float4 a = *(const float4*)s, b = *(const float4*)(s + 4);
    o[0] = f2bfbits(a.x); o[1] = f2bfbits(a.y); o[2] = f2bfbits(a.z); o[3] = f2bfbits(a.w);
    o[4] = f2bfbits(b.x); o[5] = f2bfbits(b.y); o[6] = f2bfbits(b.z); o[7] = f2bfbits(b.w);
  } else {
#pragma unroll
    for (int j = 0; j < 8; j++) o[j] = f2bfbits(c8 + j < K ? s[j] : 0.f);
  }
  *(short8*)&out[(size_t)r * Kp + c8] = o;
}

__global__ void cast8(const float* __restrict__ in, bf16* __restrict__ out, int n8) {
  int i = blockIdx.x * blockDim.x + threadIdx.x;
  if (i >= n8) return;
  const float* s = in + (size_t)i * 8;
  float4 a = *(const float4*)s, b = *(const float4*)(s + 4);
  short8 o;
  o[0] = f2bfbits(a.x); o[1] = f2bfbits(a.y); o[2] = f2bfbits(a.z); o[3] = f2bfbits(a.w);
  o[4] = f2bfbits(b.x); o[5] = f2bfbits(b.y); o[6] = f2bfbits(b.z); o[7] = f2bfbits(b.w);
  *(short8*)&out[(size_t)i * 8] = o;
}

// LDS-tiled transpose+cast: out[Np][Kp] = in[K][N]^T (zero pad)
__global__ void transpose_cast_bf(const float* __restrict__ in, bf16* __restrict__ out,
                                  int K, int N, int Kp, int Np) {
  __shared__ float tile[32][33];
  int k0 = blockIdx.x * 32, n0 = blockIdx.y * 32;
  int tx = threadIdx.x, ty = threadIdx.y;   // 32 x 8
#pragma unroll
  for (int j = 0; j < 32; j += 8) {
    int k = k0 + ty + j, n = n0 + tx;
    tile[ty + j][tx] = (k < K && n < N) ? in[(size_t)k * N + n] : 0.f;
  }
  __syncthreads();
#pragma unroll
  for (int j = 0; j < 32; j += 8) {
    int n = n0 + ty + j, k = k0 + tx;
    if (n < Np && k < Kp) out[(size_t)n * Kp + k] = __float2bfloat16(tile[tx][ty + j]);
  }
}

// ---------------------------------------------------------------- MFMA GEMM
// C[M,N] = act(A[M,K]bf16 @ Bt[N,K]bf16^T + bias).  128x128 tile, BK=32,
// 4 waves (2x2), each wave 64x64 = 4x4 16x16x32 fragments (m97 structure).
template<int RELU, int OUT_F32, int CONCAT_LI>
__global__ __launch_bounds__(256) void gemm_mfma(
    const bf16* __restrict__ A, const bf16* __restrict__ Bt,
    const float* __restrict__ bias, void* __restrict__ Cout,
    const float* __restrict__ li, int M, int N, int K)
{
  __shared__ __align__(16) unsigned short sA[128 * 32];
  __shared__ __align__(16) unsigned short sB[128 * 32];
  const int nBN = N >> 7;
  const int bm = blockIdx.x / nBN, bn = blockIdx.x - bm * nBN;
  const size_t m0 = (size_t)bm << 7, n0 = (size_t)bn << 7;
  const int t = threadIdx.x;
  const int lane = t & 63, wave = t >> 6;
  const int wr = wave >> 1, wc = wave & 1;
  const int srow = t >> 2;            // 0..63 staging row
  const int scol = (t & 3) << 3;      // bf16 col offset (8-elem chunks)
  const bf16* Ab = A + (m0 + srow) * (size_t)K + scol;
  const bf16* Bb = Bt + (n0 + srow) * (size_t)K + scol;
  unsigned short* sAd = &sA[srow * 32 + scol];
  unsigned short* sBd = &sB[srow * 32 + scol];
  const int lr = lane & 15;
  const int lk = (lane >> 4) << 3;

  f32x4 zero = {0.f, 0.f, 0.f, 0.f};
  f32x4 acc[4][4];
#pragma unroll
  for (int i = 0; i < 4; i++)
#pragma unroll
    for (int j = 0; j < 4; j++) acc[i][j] = zero;

  for (int k0 = 0; k0 < K; k0 += 32) {
    load16_g2l(Ab + k0, sAd);
    load16_g2l(Ab + (size_t)64 * K + k0, sAd + 64 * 32);
    load16_g2l(Bb + k0, sBd);
    load16_g2l(Bb + (size_t)64 * K + k0, sBd + 64 * 32);
    __syncthreads();
    short8 af[4], bv[4];
#pragma unroll
    for (int i = 0; i < 4; i++) af[i] = *(const short8*)&sA[(wr * 64 + i * 16 + lr) * 32 + lk];
#pragma unroll
    for (int i = 0; i < 4; i++) bv[i] = *(const short8*)&sB[(wc * 64 + i * 16 + lr) * 32 + lk];
#pragma unroll
    for (int i = 0; i < 4; i++)
#pragma unroll
      for (int j = 0; j < 4; j++)
        acc[i][j] = __builtin_amdgcn_mfma_f32_16x16x32_bf16(af[i], bv[j], acc[i][j], 0, 0, 0);
    __syncthreads();
  }

  // epilogue: C row=(lane>>4)*4+v, col=lane&15 per fragment (m89/m91 layout)
  const int crow = wr * 64, ccol = wc * 64;
#pragma unroll
  for (int i = 0; i < 4; i++) {
#pragma unroll
    for (int j = 0; j < 4; j++) {
      const size_t gc = n0 + ccol + j * 16 + lr;
      const bool isLi = CONCAT_LI && (gc == (size_t)(N - 1));
      float bvf = (!isLi && bias) ? bias[gc] : 0.f;
#pragma unroll
      for (int v = 0; v < 4; v++) {
        const size_t gr = m0 + crow + i * 16 + (lane >> 4) * 4 + v;
        float val = acc[i][j][v] + bvf;
        if (RELU) val = fmaxf(val, 0.f);
        if (isLi) val = li[gr];                      // concat ami_dis_li (no relu/bias)
        if (OUT_F32) ((float*)Cout)[gr * N + gc] = val;
        else ((bf16*)Cout)[gr * N + gc] = __float2bfloat16(val);
      }
    }
  }
}

// ---------------------------------------------------------------- SIMT GEMM (small)
template<int RELU, int BN>
__global__ void gemm_simt(const float* __restrict__ A, const float* __restrict__ W,
                          const float* __restrict__ bias, const float* __restrict__ vnadd,
                          const float* __restrict__ bng, const float* __restrict__ bnb,
                          const float* __restrict__ bnm, const float* __restrict__ bnv,
                          float* __restrict__ C, int M, int N, int K)
{
  int idx = blockIdx.x * blockDim.x + threadIdx.x;
  if (idx >= M * N) return;
  int m = idx / N, n = idx - m * N;
  const float* a = A + (size_t)m * K;
  float acc = bias[n];
  if (vnadd) acc += 0.2f * vnadd[n];
  for (int k = 0; k < K; k++) acc = fmaf(a[k], W[(size_t)k * N + n], acc);
  if (BN) acc = (acc - bnm[n]) * rsqrtf(bnv[n] + 1e-5f) * bng[n] + bnb[n];
  if (RELU) acc = fmaxf(acc, 0.f);
  C[idx] = acc;
}

// ---------------------------------------------------------------- CSR build
// edges e<E come from (srcA,dstA[,w]); e>=E are self-loops (s=t=e-E, w=1)
__global__ void hist_csr(const int* __restrict__ dstA, int E, int Etot, int* __restrict__ cnt) {
  int e = blockIdx.x * blockDim.x + threadIdx.x;
  if (e >= Etot) return;
  int t = (e < E) ? dstA[e] : e - E;
  atomicAdd(&cnt[t], 1);
}

// single-block exclusive scan (1024 threads, shfl within wave)
__global__ void exscan(const int* __restrict__ cnt, int* __restrict__ base, int n) {
  const int tid = threadIdx.x, lane = tid & 63, wid = tid >> 6;  // 16 waves
  __shared__ int wsum[16];
  __shared__ int woff[17];
  __shared__ int carry;
  if (tid == 0) carry = 0;
  __syncthreads();
  for (int off = 0; off < n; off += 1024) {
    int i = off + tid;
    int v = (i < n) ? cnt[i] : 0;
    int iv = v;
#pragma unroll
    for (int s = 1; s < 64; s <<= 1) {
      int tt = __shfl_up(iv, s);
      if (lane >= s) iv += tt;
    }
    if (lane == 63) wsum[wid] = iv;
    __syncthreads();
    if (tid == 0) {
      int run = 0;
      for (int j = 0; j < 16; j++) { woff[j] = run; run += wsum[j]; }
      woff[16] = run;
    }
    __syncthreads();
    if (i < n) base[i] = carry + woff[wid] + iv - v;
    __syncthreads();
    if (tid == 0) carry += woff[16];
    __syncthreads();
  }
  if (threadIdx.x == 0) base[n] = carry;
}

__global__ void fill_csr(const int* __restrict__ srcA, const int* __restrict__ dstA,
                         const float* __restrict__ w, const float* __restrict__ dinv,
                         const int* __restrict__ base, int* __restrict__ cur,
                         int2* __restrict__ rec, int E, int Etot) {
  int e = blockIdx.x * blockDim.x + threadIdx.x;
  if (e >= Etot) return;
  int s, t; float ww = 1.f;
  if (e < E) { s = srcA[e]; t = dstA[e]; if (w) ww = w[e]; }
  else { s = t = e - E; }
  int pos = base[t] + atomicAdd(&cur[t], 1);
  float nrm = dinv ? (dinv[s] * ww * dinv[t]) : 0.f;
  rec[pos] = make_int2(s, __float_as_int(nrm));
}

// ---------------------------------------------------------------- GCN pieces
__global__ void deg_kernel(const int* __restrict__ col, const float* __restrict__ w,
                           float* __restrict__ deg, int E) {
  int e = blockIdx.x * blockDim.x + threadIdx.x;
  if (e < E) atomicAdd(&deg[col[e]], w[e]);
}

__global__ void dinv_kernel(const float* __restrict__ deg, float* __restrict__ dinv, int n) {
  int i = blockIdx.x * blockDim.x + threadIdx.x;
  if (i >= n) return;
  float d = deg[i] + 1.0f;                       // + self-loop weight 1
  dinv[i] = d > 0.f ? rsqrtf(fmaxf(d, 1e-12f)) : 0.f;
}

// gather aggregation: 1 wave per node, lane owns float2 of 128 dims.
// aout = bf16 activation (next layer GEMM input); pool += relu'd value.
__global__ void gcn_gather(const int* __restrict__ base, const int2* __restrict__ rec,
                           const float* __restrict__ h, const float* __restrict__ bias,
                           bf16* __restrict__ aout, float* __restrict__ pool,
                           const int* __restrict__ batch, int n) {
  int wid = threadIdx.x >> 6, lane = threadIdx.x & 63;
  int node = blockIdx.x * 4 + wid;
  if (node >= n) return;
  int s0 = base[node], s1 = base[node + 1];
  float2 acc = {0.f, 0.f};
  for (int p = s0; p < s1; p++) {
    int2 r = rec[p];
    float nrm = __int_as_float(r.y);
    float2 hv = *(const float2*)&h[(size_t)r.x * 128 + lane * 2];
    acc.x += hv.x * nrm; acc.y += hv.y * nrm;
  }
  int d0 = lane * 2;
  float v0 = fmaxf(acc.x + bias[d0], 0.f);
  float v1 = fmaxf(acc.y + bias[d0 + 1], 0.f);
  __hip_bfloat162 pr; pr.x = __float2bfloat16(v0); pr.y = __float2bfloat16(v1);
  *(__hip_bfloat162*)&aout[(size_t)node * 128 + d0] = pr;
  int g = batch[node];
  atomicAdd(&pool[(size_t)g * 128 + d0], v0);
  atomicAdd(&pool[(size_t)g * 128 + d0 + 1], v1);
}

// ---------------------------------------------------------------- GAT pieces
__global__ void gat_uv(const float* __restrict__ h, const float* __restrict__ as,
                       const float* __restrict__ ad, float* __restrict__ u,
                       float* __restrict__ v, int n) {
  int wave = threadIdx.x >> 6, lane = threadIdx.x & 63;
  int row = blockIdx.x * 4 + wave;
  if (row >= n) return;
  const float* hr = h + (size_t)row * 128;
  float su = 0.f, sv = 0.f;
  for (int d = lane; d < 128; d += 64) { float x = hr[d]; su += x * as[d]; sv += x * ad[d]; }
  for (int off = 32; off; off >>= 1) { su += __shfl_down(su, off); sv += __shfl_down(sv, off); }
  if (lane == 0) { u[row] = su; v[row] = sv; }
}

// full per-node softmax + weighted gather; 1 wave per node.
__global__ void gat_gather(const int* __restrict__ base, const int2* __restrict__ rec,
                           const float* __restrict__ u, const float* __restrict__ vv,
                           const float* __restrict__ h, const float* __restrict__ bias,
                           float* __restrict__ xout, float* __restrict__ pool,
                           const int* __restrict__ batch, int n) {
  int wid = threadIdx.x >> 6, lane = threadIdx.x & 63;
  int node = blockIdx.x * 4 + wid;
  if (node >= n) return;
  int s0 = base[node], s1 = base[node + 1];
  float vt = vv[node];
  float m = -3.4e38f;
  for (int p = s0 + lane; p < s1; p += 64) {
    float lg = u[rec[p].x] + vt; lg = lg >= 0.f ? lg : 0.2f * lg;
    m = fmaxf(m, lg);
  }
#pragma unroll
  for (int s = 32; s; s >>= 1) m = fmaxf(m, __shfl_xor(m, s));
  float ssum = 0.f;
  for (int p = s0 + lane; p < s1; p += 64) {
    float lg = u[rec[p].x] + vt; lg = lg >= 0.f ? lg : 0.2f * lg;
    ssum += __expf(lg - m);
  }
#pragma unroll
  for (int s = 32; s; s >>= 1) ssum += __shfl_xor(ssum, s);
  float rs = 1.f / ssum;
  float2 acc = {0.f, 0.f};
  for (int p = s0; p < s1; p++) {
    int2 r = rec[p];
    float lg = u[r.x] + vt; lg = lg >= 0.f ? lg : 0.2f * lg;
    float alpha = __expf(lg - m) * rs;
    float2 hv = *(const float2*)&h[(size_t)r.x * 128 + lane * 2];
    acc.x += hv.x * alpha; acc.y += hv.y * alpha;
  }
  int d0 = lane * 2;
  float v0 = fmaxf(acc.x + bias[d0], 0.f);
  float v1 = fmaxf(acc.y + bias[d0 + 1], 0.f);
  if (xout) *(float2*)&xout[(size_t)node * 128 + d0] = make_float2(v0, v1);
  int g = batch[node];
  atomicAdd(&pool[(size_t)g * 128 + d0], v0);
  atomicAdd(&pool[(size_t)g * 128 + d0 + 1], v1);
}

// ---------------------------------------------------------------- elementwise
__global__ void cnt_kernel(const int* __restrict__ batch, float* __restrict__ cnt, int n) {
  int i = blockIdx.x * blockDim.x + threadIdx.x;
  if (i < n) atomicAdd(&cnt[batch[i]], 1.0f);
}

__global__ void pool_div(const float* __restrict__ pool, const float* __restrict__ cnt,
                         float* __restrict__ out, int n) {
  int i = blockIdx.x * blockDim.x + threadIdx.x;
  if (i < n) out[i] = pool[i] / fmaxf(cnt[i >> 7], 1.f);
}

__global__ void fill_t(float* __restrict__ t, const float* __restrict__ vn, int n) {
  int i = blockIdx.x * blockDim.x + threadIdx.x;
  if (i < n) t[i] = vn[i & 127];
}

__global__ void scatter_t(const float* __restrict__ x, const int* __restrict__ batch,
                          float* __restrict__ t, int n) {
  int gi = blockIdx.x * blockDim.x + threadIdx.x;
  if (gi >= n) return;
  int i = gi >> 7, d = gi & 127;
  atomicAdd(&t[(size_t)batch[i] * 128 + d], x[gi]);
}

__global__ void add_drug(const float* __restrict__ x11, const float* __restrict__ dr,
                         const int* __restrict__ batch, float* __restrict__ out, int n) {
  int gi = blockIdx.x * blockDim.x + threadIdx.x;
  if (gi >= n) return;
  int i = gi >> 7, d = gi & 127;
  out[gi] = x11[gi] + 0.2f * dr[(size_t)batch[i] * 128 + d];
}

__global__ void concat_k(const float* __restrict__ xg, const float* __restrict__ ami,
                         float* __restrict__ z, int n) {
  int i = blockIdx.x * blockDim.x + threadIdx.x;
  if (i >= n) return;
  int b = i >> 8, d = i & 255;
  z[i] = d < 128 ? xg[(b << 7) + d] : ami[(b << 7) + d - 128];
}

__global__ void relu_k(const float* __restrict__ in, float* __restrict__ out, int n) {
  int i = blockIdx.x * blockDim.x + threadIdx.x;
  if (i < n) out[i] = fmaxf(in[i], 0.f);
}

// ---------------------------------------------------------------- launch
static inline int cdiv(int a, int b) { return (a + b - 1) / b; }

extern "C" void kernel_launch(void* const* d_in, const int* in_sizes, int n_in,
                              void* d_out, int out_size, void* d_ws, size_t ws_size,
                              hipStream_t stream)
{
  const float* x1      = (const float*)d_in[0];
  const float* x3      = (const float*)d_in[1];
  const float* ami_dis = (const float*)d_in[2];
  const float* ami_li  = (const float*)d_in[3];
  const float* fc00_w = (const float*)d_in[4];  const float* fc00_b = (const float*)d_in[5];
  const float* fc01_w = (const float*)d_in[6];  const float* fc01_b = (const float*)d_in[7];
  const float* fc02_w = (const float*)d_in[8];  const float* fc02_b = (const float*)d_in[9];
  const float* w1 = (const float*)d_in[10];     const float* b1 = (const float*)d_in[11];
  const float* w2 = (const float*)d_in[12];     const float* b2 = (const float*)d_in[13];
  const float* fc03_w = (const float*)d_in[14]; const float* fc03_b = (const float*)d_in[15];
  const float* gat_W  = (const float*)d_in[16]; const float* gat_as = (const float*)d_in[17];
  const float* gat_ad = (const float*)d_in[18]; const float* gat_bias = (const float*)d_in[19];
  const float* vn_emb = (const float*)d_in[20];
  const float* vl1_w = (const float*)d_in[21];  const float* vl1_b = (const float*)d_in[22];
  const float* bn1_g = (const float*)d_in[23];  const float* bn1_b = (const float*)d_in[24];
  const float* bn1_m = (const float*)d_in[25];  const float* bn1_v = (const float*)d_in[26];
  const float* vl2_w = (const float*)d_in[27];  const float* vl2_b = (const float*)d_in[28];
  const float* bn2_g = (const float*)d_in[29];  const float* bn2_b = (const float*)d_in[30];
  const float* bn2_m = (const float*)d_in[31];  const float* bn2_v = (const float*)d_in[32];
  const float* gcn_W = (const float*)d_in[33];  const float* gcn_b = (const float*)d_in[34];
  const float* fc1_w = (const float*)d_in[35];  const float* fc1_b = (const float*)d_in[36];
  const float* fc2_w = (const float*)d_in[37];  const float* fc2_b = (const float*)d_in[38];
  const float* fc3_w = (const float*)d_in[39];  const float* fc3_b = (const float*)d_in[40];
  const float* out_w = (const float*)d_in[41];  const float* out_b = (const float*)d_in[42];
  const int* drug_ei   = (const int*)d_in[43];
  const int* ami_ei    = (const int*)d_in[44];
  const int* batch1    = (const int*)d_in[45];
  const int* ami_batch = (const int*)d_in[46];

  char* ws = (char*)d_ws;
  // ---- small persistent arena (< 8.4 MB)
  bf16*  Bt0   = (bf16*)(ws + 0);          // 1024x1920
  bf16*  Bt1   = (bf16*)(ws + 3932160);    // 512x1024
  bf16*  Bt2   = (bf16*)(ws + 4980736);    // 128x512 (row127=0)
  bf16*  BtGCN = (bf16*)(ws + 5111808);    // 3x128x128
  bf16*  BtGAT = (bf16*)(ws + 5210112);    // 3x128x128
  float* deg   = (float*)(ws + 5308416);
  float* dinv  = (float*)(ws + 5410816);
  float* pool_ami  = (float*)(ws + 5513216);
  float* pool_drug = (float*)(ws + 5644288);
  float* cnt_ami   = (float*)(ws + 5775360);
  float* cnt_drug  = (float*)(ws + 5776384);
  float* amivec    = (float*)(ws + 5777408);
  float* xg        = (float*)(ws + 5908480);
  float* uarr  = (float*)(ws + 6039552);
  float* varr  = (float*)(ws + 6080512);
  float* tbuf  = (float*)(ws + 6572032);   // 256x128
  float* t2buf = (float*)(ws + 6703104);   // 256x256
  float* drugv = (float*)(ws + 6965248);   // 256x128
  float* zbuf  = (float*)(ws + 7096320);   // 256x256
  float* z2buf = (float*)(ws + 7358464);   // 256x512
  float* z3buf = (float*)(ws + 7882752);   // 256x256
  float* z4buf = (float*)(ws + 8144896);   // 256x128

  // ---- arena A (98.3 MB, aliased across phases)
  const size_t AA = 8388608;
  bf16*  A3bf = (bf16*)(ws + AA);                    // 25600x1920 (dead after fc00)
  bf16*  a2bf = (bf16*)(ws + AA);                    // 25600x512  (after fc01)
  bf16*  abf  = (bf16*)(ws + AA + 41943040);         // 25600x128 bf16 activation
  float* hG   = (float*)(ws + AA + 52428800);        // 25600x128 f32
  // CSR (built after fc00; lives in A3bf's dead tail)
  int*  base3 = (int*) (ws + AA + 68157440);         // 25601 ints
  int*  cur3  = (int*) (ws + AA + 68812800);         // 25600 ints
  int2* rec3  = (int2*)(ws + AA + 69206016);         // 844800 x 8B
  int*  base1 = (int*) (ws + AA + 77594624);         // 10241 ints
  int*  cur1  = (int*) (ws + AA + 78118912);         // 10240 ints
  int2* rec1  = (int2*)(ws + AA + 78643200);         // 92160 x 8B
  // drug phase (ami arrays dead by then; all < AA+41.9MB)
  float* h1    = (float*)(ws + AA + 0);              // 10240x128
  float* hd2   = (float*)(ws + AA + 5242880);        // 10240x64
  float* xdrug = (float*)(ws + AA + 7864320);        // 10240x128
  float* x11   = (float*)(ws + AA + 13107200);
  float* x2b   = (float*)(ws + AA + 18350080);
  bf16*  xbf   = (bf16*) (ws + AA + 23592960);
  bf16*  xbf2  = (bf16*) (ws + AA + 26214400);
  float* hgat  = (float*)(ws + AA + 28835840);
  // ---- arena B
  const size_t ABo = AA + 98304000;
  bf16*  a1bf = (bf16*)(ws + ABo);                   // 25600x1024 (total ~159.1 MB)

  const int Etot3 = EE3 + NN3, Etot1 = EE1 + NN1;

  // ================= prep: weight transposes (tiled) + x3 cast =================
  {
    dim3 b(32, 8);
    transpose_cast_bf<<<dim3(60, 32), b, 0, stream>>>(fc00_w, Bt0, 1900, 1024, 1920, 1024);
    transpose_cast_bf<<<dim3(32, 16), b, 0, stream>>>(fc01_w, Bt1, 1024, 512, 1024, 512);
    transpose_cast_bf<<<dim3(16, 4), b, 0, stream>>>(fc02_w, Bt2, 512, 127, 512, 128);
    for (int l = 0; l < 3; l++) {
      transpose_cast_bf<<<dim3(4, 4), b, 0, stream>>>(gcn_W + l * 16384, BtGCN + l * 16384, 128, 128, 128, 128);
      transpose_cast_bf<<<dim3(4, 4), b, 0, stream>>>(gat_W + l * 16384, BtGAT + l * 16384, 128, 128, 128, 128);
    }
  }
  cast_pad8<<<cdiv(25600 * 240, 256), 256, 0, stream>>>(x3, A3bf, 25600, 1900, 1920);

  // ================= ami branch: MLP (bf16 MFMA) =================
  gemm_mfma<1, 0, 0><<<200 * 8, 256, 0, stream>>>(A3bf, Bt0, fc00_b, a1bf, nullptr, 25600, 1024, 1920);
  // A3bf dead -> CSR arena usable from here
  gemm_mfma<1, 0, 0><<<200 * 4, 256, 0, stream>>>(a1bf, Bt1, fc01_b, a2bf, nullptr, 25600, 512, 1024);
  gemm_mfma<1, 0, 1><<<200 * 1, 256, 0, stream>>>(a2bf, Bt2, fc02_b, abf, ami_li, 25600, 128, 512);

  // ================= graph prep: degrees, counts, CSR build =================
  hipMemsetAsync(deg, 0, 102400, stream);
  hipMemsetAsync(pool_ami, 0, 131072, stream);
  hipMemsetAsync(pool_drug, 0, 131072, stream);
  hipMemsetAsync(cnt_ami, 0, 1024, stream);
  hipMemsetAsync(cnt_drug, 0, 1024, stream);
  deg_kernel<<<cdiv(EE3, 256), 256, 0, stream>>>(ami_ei + EE3, ami_dis, deg, EE3);
  dinv_kernel<<<cdiv(NN3, 256), 256, 0, stream>>>(deg, dinv, NN3);
  cnt_kernel<<<cdiv(NN3, 256), 256, 0, stream>>>(ami_batch, cnt_ami, NN3);
  cnt_kernel<<<cdiv(NN1, 256), 256, 0, stream>>>(batch1, cnt_drug, NN1);

  // GCN CSR (dst-keyed, self-loops appended, nrm precomputed)
  hipMemsetAsync(cur3, 0, 102400, stream);
  hist_csr<<<cdiv(Etot3, 256), 256, 0, stream>>>(ami_ei + EE3, EE3, Etot3, cur3);
  exscan<<<1, 1024, 0, stream>>>(cur3, base3, NN3);
  hipMemsetAsync(cur3, 0, 102400, stream);
  fill_csr<<<cdiv(Etot3, 256), 256, 0, stream>>>(ami_ei, ami_ei + EE3, ami_dis, dinv,
                                                 base3, cur3, rec3, EE3, Etot3);
  // GAT CSR
  hipMemsetAsync(cur1, 0, 40960, stream);
  hist_csr<<<cdiv(Etot1, 256), 256, 0, stream>>>(drug_ei + EE1, EE1, Etot1, cur1);
  exscan<<<1, 1024, 0, stream>>>(cur1, base1, NN1);
  hipMemsetAsync(cur1, 0, 40960, stream);
  fill_csr<<<cdiv(Etot1, 256), 256, 0, stream>>>(drug_ei, drug_ei + EE1, nullptr, nullptr,
                                                 base1, cur1, rec1, EE1, Etot1);

  // ================= 3x GCN (gather, no atom-scatter) =================
  for (int l = 0; l < 3; l++) {
    gemm_mfma<0, 1, 0><<<200, 256, 0, stream>>>(abf, BtGCN + l * 16384, nullptr, hG, nullptr, NN3, 128, 128);
    gcn_gather<<<cdiv(NN3, 4), 256, 0, stream>>>(base3, rec3, hG, gcn_b + l * 128,
                                                 abf, pool_ami, ami_batch, NN3);
  }
  pool_div<<<cdiv(BB * 128, 256), 256, 0, stream>>>(pool_ami, cnt_ami, amivec, BB * 128);

  // ================= drug branch: MLP (vn folded into fc03 bias) ==========
  gemm_simt<1, 0><<<cdiv(NN1 * 128, 256), 256, 0, stream>>>(x1, w1, b1, nullptr, nullptr, nullptr, nullptr, nullptr, h1, NN1, 128, 52);
  gemm_simt<1, 0><<<cdiv(NN1 * 64, 256), 256, 0, stream>>>(h1, w2, b2, nullptr, nullptr, nullptr, nullptr, nullptr, hd2, NN1, 64, 128);
  gemm_simt<0, 0><<<cdiv(NN1 * 128, 256), 256, 0, stream>>>(hd2, fc03_w, fc03_b, vn_emb, nullptr, nullptr, nullptr, nullptr, xdrug, NN1, 128, 64);
  cast8<<<cdiv(NN1 * 16, 256), 256, 0, stream>>>(xdrug, xbf, NN1 * 16);

  // ================= GAT layer 0 =================
  gemm_mfma<0, 1, 0><<<80, 256, 0, stream>>>(xbf, BtGAT, nullptr, hgat, nullptr, NN1, 128, 128);
  gat_uv<<<cdiv(NN1, 4), 256, 0, stream>>>(hgat, gat_as, gat_ad, uarr, varr, NN1);
  gat_gather<<<cdiv(NN1, 4), 256, 0, stream>>>(base1, rec1, uarr, varr, hgat, gat_bias,
                                               x11, pool_drug, batch1, NN1);

  // ================= virtual-node update =================
  fill_t<<<cdiv(BB * 128, 256), 256, 0, stream>>>(tbuf, vn_emb, BB * 128);
  scatter_t<<<cdiv(NN1 * 128, 256), 256, 0, stream>>>(x11, batch1, tbuf, NN1 * 128);
  gemm_simt<1, 1><<<cdiv(BB * 256, 256), 256, 0, stream>>>(tbuf, vl1_w, vl1_b, nullptr, bn1_g, bn1_b, bn1_m, bn1_v, t2buf, BB, 256, 128);
  gemm_simt<1, 1><<<cdiv(BB * 128, 256), 256, 0, stream>>>(t2buf, vl2_w, vl2_b, nullptr, bn2_g, bn2_b, bn2_m, bn2_v, drugv, BB, 128, 256);
  add_drug<<<cdiv(NN1 * 128, 256), 256, 0, stream>>>(x11, drugv, batch1, x2b, NN1 * 128);
  cast8<<<cdiv(NN1 * 16, 256), 256, 0, stream>>>(x2b, xbf2, NN1 * 16);

  // ================= GAT layers 1,2 (shared input x2b) =================
  for (int l = 1; l < 3; l++) {
    gemm_mfma<0, 1, 0><<<80, 256, 0, stream>>>(xbf2, BtGAT + l * 16384, nullptr, hgat, nullptr, NN1, 128, 128);
    gat_uv<<<cdiv(NN1, 4), 256, 0, stream>>>(hgat, gat_as + l * 128, gat_ad + l * 128, uarr, varr, NN1);
    gat_gather<<<cdiv(NN1, 4), 256, 0, stream>>>(base1, rec1, uarr, varr, hgat, gat_bias + l * 128,
                                                 nullptr, pool_drug, batch1, NN1);
  }
  pool_div<<<cdiv(BB * 128, 256), 256, 0, stream>>>(pool_drug, cnt_drug, xg, BB * 128);

  // ================= fused head =================
  concat_k<<<cdiv(BB * 256, 256), 256, 0, stream>>>(xg, amivec, zbuf, BB * 256);
  float* h2out = (float*)d_out + 256;     // output tuple: (out[256], h2[256x512])
  gemm_simt<0, 0><<<cdiv(BB * 512, 256), 256, 0, stream>>>(zbuf, fc1_w, fc1_b, nullptr, nullptr, nullptr, nullptr, nullptr, h2out, BB, 512, 256);
  relu_k<<<cdiv(BB * 512, 256), 256, 0, stream>>>(h2out, z2buf, BB * 512);
  gemm_simt<1, 0><<<cdiv(BB * 256, 256), 256, 0, stream>>>(z2buf, fc2_w, fc2_b, nullptr, nullptr, nullptr, nullptr, nullptr, z3buf, BB, 256, 512);
  gemm_simt<1, 0><<<cdiv(BB * 128, 256), 256, 0, stream>>>(z3buf, fc3_w, fc3_b, nullptr, nullptr, nullptr, nullptr, nullptr, z4buf, BB, 128, 256);
  gemm_simt<0, 0><<<1, 256, 0, stream>>>(z4buf, out_w, out_b, nullptr, nullptr, nullptr, nullptr, nullptr, (float*)d_out, BB, 1, 128);
}

// Round 5
// 1749.085 us; speedup vs baseline: 1.6695x; 1.1606x over previous
//
#include <hip/hip_runtime.h>
#include <hip/hip_bf16.h>
#include <stdint.h>

typedef __hip_bfloat16 bf16;
typedef __attribute__((ext_vector_type(8))) short short8;   // 8 bf16 in 4 VGPRs
typedef __attribute__((ext_vector_type(4))) float f32x4;

#define BB 256
#define NN1 10240
#define EE1 81920
#define NN3 25600
#define EE3 819200

// ---------------------------------------------------------------- helpers
__device__ __forceinline__ void load16_g2l(const void* g, void* l) {
  __builtin_amdgcn_global_load_lds(
      (const __attribute__((address_space(1))) void*)(uintptr_t)g,
      (__attribute__((address_space(3))) void*)(uintptr_t)l, 16, 0, 0);
}

__device__ __forceinline__ unsigned short f2bfbits(float v) {
  bf16 t = __float2bfloat16(v);
  union { bf16 b; unsigned short u; } x; x.b = t; return x.u;
}

// ---------------------------------------------------------------- casts
__global__ void cast_pad8(const float* __restrict__ in, bf16* __restrict__ out,
                          int M, int K, int Kp) {
  int nch = Kp >> 3;
  int i = blockIdx.x * blockDim.x + threadIdx.x;
  if (i >= M * nch) return;
  int r = i / nch, c8 = (i - r * nch) << 3;
  const float* s = in + (size_t)r * K + c8;
  short8 o;
  if (c8 + 8 <= K) {
    float4 a = *(const float4*)s, b = *(const float4*)(s + 4);
    o[0] = f2bfbits(a.x); o[1] = f2bfbits(a.y); o[2] = f2bfbits(a.z); o[3] = f2bfbits(a.w);
    o[4] = f2bfbits(b.x); o[5] = f2bfbits(b.y); o[6] = f2bfbits(b.z); o[7] = f2bfbits(b.w);
  } else {
#pragma unroll
    for (int j = 0; j < 8; j++) o[j] = f2bfbits(c8 + j < K ? s[j] : 0.f);
  }
  *(short8*)&out[(size_t)r * Kp + c8] = o;
}

// LDS-tiled transpose+cast: out[Np][Kp] = in[K][N]^T (zero pad); z = layer (stride K*N / Np*Kp)
__global__ void transpose_cast_bf(const float* __restrict__ in, bf16* __restrict__ out,
                                  int K, int N, int Kp, int Np) {
  __shared__ float tile[32][33];
  in  += (size_t)blockIdx.z * K * N;
  out += (size_t)blockIdx.z * Kp * Np;
  int k0 = blockIdx.x * 32, n0 = blockIdx.y * 32;
  int tx = threadIdx.x, ty = threadIdx.y;   // 32 x 8
#pragma unroll
  for (int j = 0; j < 32; j += 8) {
    int k = k0 + ty + j, n = n0 + tx;
    tile[ty + j][tx] = (k < K && n < N) ? in[(size_t)k * N + n] : 0.f;
  }
  __syncthreads();
#pragma unroll
  for (int j = 0; j < 32; j += 8) {
    int n = n0 + ty + j, k = k0 + tx;
    if (n < Np && k < Kp) out[(size_t)n * Kp + k] = __float2bfloat16(tile[tx][ty + j]);
  }
}

// ---------------------------------------------------------------- MFMA GEMM
// C[M,N] = act(A[M,K]bf16 @ Bt[N,K]bf16^T + bias).  128x128 tile, BK=32,
// 4 waves (2x2), wave = 64x64 = 4x4 16x16x32 frags (m97 structure) + XCD swizzle.
template<int RELU, int OUT_F32, int CONCAT_LI, int POOL>
__global__ __launch_bounds__(256) void gemm_mfma(
    const bf16* __restrict__ A, const bf16* __restrict__ Bt,
    const float* __restrict__ bias, void* __restrict__ Cout,
    const float* __restrict__ li, float* __restrict__ pool,
    const int* __restrict__ batch, int M, int N, int K)
{
  __shared__ __align__(16) unsigned short sA[128 * 32];
  __shared__ __align__(16) unsigned short sB[128 * 32];
  const int nBN = N >> 7;
  // XCD-chunked swizzle (T1): grid always divisible by 8 here
  int bid = blockIdx.x, nwg = gridDim.x;
  int swz = (nwg & 7) ? bid : ((bid & 7) * (nwg >> 3) + (bid >> 3));
  const int bm = swz / nBN, bn = swz - bm * nBN;
  const size_t m0 = (size_t)bm << 7, n0 = (size_t)bn << 7;
  const int t = threadIdx.x;
  const int lane = t & 63, wave = t >> 6;
  const int wr = wave >> 1, wc = wave & 1;
  const int srow = t >> 2;            // 0..63 staging row
  const int scol = (t & 3) << 3;      // bf16 col offset (8-elem chunks)
  const bf16* Ab = A + (m0 + srow) * (size_t)K + scol;
  const bf16* Bb = Bt + (n0 + srow) * (size_t)K + scol;
  unsigned short* sAd = &sA[srow * 32 + scol];
  unsigned short* sBd = &sB[srow * 32 + scol];
  const int lr = lane & 15;
  const int lk = (lane >> 4) << 3;

  f32x4 zero = {0.f, 0.f, 0.f, 0.f};
  f32x4 acc[4][4];
#pragma unroll
  for (int i = 0; i < 4; i++)
#pragma unroll
    for (int j = 0; j < 4; j++) acc[i][j] = zero;

  for (int k0 = 0; k0 < K; k0 += 32) {
    load16_g2l(Ab + k0, sAd);
    load16_g2l(Ab + (size_t)64 * K + k0, sAd + 64 * 32);
    load16_g2l(Bb + k0, sBd);
    load16_g2l(Bb + (size_t)64 * K + k0, sBd + 64 * 32);
    __syncthreads();
    short8 af[4], bv[4];
#pragma unroll
    for (int i = 0; i < 4; i++) af[i] = *(const short8*)&sA[(wr * 64 + i * 16 + lr) * 32 + lk];
#pragma unroll
    for (int i = 0; i < 4; i++) bv[i] = *(const short8*)&sB[(wc * 64 + i * 16 + lr) * 32 + lk];
#pragma unroll
    for (int i = 0; i < 4; i++)
#pragma unroll
      for (int j = 0; j < 4; j++)
        acc[i][j] = __builtin_amdgcn_mfma_f32_16x16x32_bf16(af[i], bv[j], acc[i][j], 0, 0, 0);
    __syncthreads();
  }

  // epilogue: C row=(lane>>4)*4+v, col=lane&15 per fragment (m89/m91 layout)
  const int crow = wr * 64, ccol = wc * 64;
#pragma unroll
  for (int i = 0; i < 4; i++) {
#pragma unroll
    for (int v = 0; v < 4; v++) {
      const size_t gr = m0 + crow + i * 16 + (lane >> 4) * 4 + v;
      const int bt = POOL ? batch[gr] : 0;
      const float liv = CONCAT_LI ? li[gr] : 0.f;
#pragma unroll
      for (int j = 0; j < 4; j++) {
        const size_t gc = n0 + ccol + j * 16 + lr;
        const bool isLi = CONCAT_LI && (gc == (size_t)(N - 1));
        float val = acc[i][j][v] + ((!isLi && bias) ? bias[gc] : 0.f);
        if (RELU) val = fmaxf(val, 0.f);
        if (isLi) val = liv;                         // concat ami_dis_li (no relu/bias)
        if (OUT_F32) ((float*)Cout)[gr * N + gc] = val;
        else ((bf16*)Cout)[gr * N + gc] = __float2bfloat16(val);
        if (POOL) atomicAdd(&pool[(size_t)bt * 128 + gc], val);
      }
    }
  }
}

// ---------------------------------------------------------------- SIMT GEMM (small, BN fused)
template<int RELU, int BN>
__global__ void gemm_simt(const float* __restrict__ A, const float* __restrict__ W,
                          const float* __restrict__ bias,
                          const float* __restrict__ bng, const float* __restrict__ bnb,
                          const float* __restrict__ bnm, const float* __restrict__ bnv,
                          float* __restrict__ C, int M, int N, int K)
{
  int idx = blockIdx.x * blockDim.x + threadIdx.x;
  if (idx >= M * N) return;
  int m = idx / N, n = idx - m * N;
  const float* a = A + (size_t)m * K;
  float acc = bias[n];
  for (int k = 0; k < K; k++) acc = fmaf(a[k], W[(size_t)k * N + n], acc);
  if (BN) acc = (acc - bnm[n]) * rsqrtf(bnv[n] + 1e-5f) * bng[n] + bnb[n];
  if (RELU) acc = fmaxf(acc, 0.f);
  C[idx] = acc;
}

// ---------------------------------------------------------------- CSR build
__global__ void hist_csr(const int* __restrict__ dstA, int E, int Etot, int* __restrict__ cnt) {
  int e = blockIdx.x * blockDim.x + threadIdx.x;
  if (e >= Etot) return;
  int t = (e < E) ? dstA[e] : e - E;
  atomicAdd(&cnt[t], 1);
}

// multi-block exclusive scan, 1024 thr/block
__global__ void scan_blocks(const int* __restrict__ cnt, int* __restrict__ base,
                            int* __restrict__ bsum, int n) {
  const int tid = threadIdx.x, lane = tid & 63, wid = tid >> 6;  // 16 waves
  __shared__ int wsum[16], woff[16];
  __shared__ int tot;
  int i = blockIdx.x * 1024 + tid;
  int v = (i < n) ? cnt[i] : 0;
  int iv = v;
#pragma unroll
  for (int s = 1; s < 64; s <<= 1) { int t = __shfl_up(iv, s); if (lane >= s) iv += t; }
  if (lane == 63) wsum[wid] = iv;
  __syncthreads();
  if (tid == 0) { int run = 0; for (int j = 0; j < 16; j++) { woff[j] = run; run += wsum[j]; } tot = run; }
  __syncthreads();
  if (i < n) base[i] = woff[wid] + iv - v;
  if (tid == 0) bsum[blockIdx.x] = tot;
}

__global__ void scan_tops(int* __restrict__ bsum, int* __restrict__ base, int n, int nb) {
  if (threadIdx.x == 0) {
    int run = 0;
    for (int j = 0; j < nb; j++) { int t = bsum[j]; bsum[j] = run; run += t; }
    base[n] = run;
  }
}

__global__ void scan_add(int* __restrict__ base, const int* __restrict__ bsum,
                         int* __restrict__ cur, int n) {
  int i = blockIdx.x * 1024 + threadIdx.x;
  if (i < n) { base[i] += bsum[blockIdx.x]; cur[i] = 0; }
}

__global__ void fill_csr(const int* __restrict__ srcA, const int* __restrict__ dstA,
                         const float* __restrict__ w, const float* __restrict__ dinv,
                         const int* __restrict__ base, int* __restrict__ cur,
                         int2* __restrict__ rec, int E, int Etot) {
  int e = blockIdx.x * blockDim.x + threadIdx.x;
  if (e >= Etot) return;
  int s, t; float ww = 1.f;
  if (e < E) { s = srcA[e]; t = dstA[e]; if (w) ww = w[e]; }
  else { s = t = e - E; }
  int pos = base[t] + atomicAdd(&cur[t], 1);
  float nrm = dinv ? (dinv[s] * ww * dinv[t]) : 0.f;
  rec[pos] = make_int2(s, __float_as_int(nrm));
}

// ---------------------------------------------------------------- GCN pieces
__global__ void deg_kernel(const int* __restrict__ col, const float* __restrict__ w,
                           float* __restrict__ deg, int E) {
  int e = blockIdx.x * blockDim.x + threadIdx.x;
  if (e < E) atomicAdd(&deg[col[e]], w[e]);
}

__global__ void dinv_kernel(const float* __restrict__ deg, float* __restrict__ dinv, int n) {
  int i = blockIdx.x * blockDim.x + threadIdx.x;
  if (i >= n) return;
  float d = deg[i] + 1.0f;                       // + self-loop weight 1
  dinv[i] = d > 0.f ? rsqrtf(fmaxf(d, 1e-12f)) : 0.f;
}

// pre-aggregation gather (GCN reordered: Y = A_hat @ X, bf16 in/out)
__global__ void gather_pre(const int* __restrict__ base, const int2* __restrict__ rec,
                           const bf16* __restrict__ x, bf16* __restrict__ y, int n) {
  int wid = threadIdx.x >> 6, lane = threadIdx.x & 63;
  int node = blockIdx.x * 4 + wid;
  if (node >= n) return;
  int s0 = base[node], s1 = base[node + 1];
  int d0 = lane * 2;
  float a0 = 0.f, a1 = 0.f;
  for (int p = s0; p < s1; p++) {
    int2 r = rec[p];
    float nrm = __int_as_float(r.y);
    __hip_bfloat162 hv = *(const __hip_bfloat162*)&x[(size_t)r.x * 128 + d0];
    a0 = fmaf(__bfloat162float(hv.x), nrm, a0);
    a1 = fmaf(__bfloat162float(hv.y), nrm, a1);
  }
  __hip_bfloat162 pr; pr.x = __float2bfloat16(a0); pr.y = __float2bfloat16(a1);
  *(__hip_bfloat162*)&y[(size_t)node * 128 + d0] = pr;
}

// ---------------------------------------------------------------- GAT pieces
__global__ void gat_uv(const bf16* __restrict__ h, const float* __restrict__ as,
                       const float* __restrict__ ad, float* __restrict__ u,
                       float* __restrict__ v, int n) {
  int wave = threadIdx.x >> 6, lane = threadIdx.x & 63;
  int row = blockIdx.x * 4 + wave;
  if (row >= n) return;
  int d0 = lane * 2;
  __hip_bfloat162 hv = *(const __hip_bfloat162*)&h[(size_t)row * 128 + d0];
  float x0 = __bfloat162float(hv.x), x1 = __bfloat162float(hv.y);
  float su = x0 * as[d0] + x1 * as[d0 + 1];
  float sv = x0 * ad[d0] + x1 * ad[d0 + 1];
#pragma unroll
  for (int off = 32; off; off >>= 1) { su += __shfl_down(su, off); sv += __shfl_down(sv, off); }
  if (lane == 0) { u[row] = su; v[row] = sv; }
}

// per-node softmax + weighted gather; 1 wave per node; h in bf16
__global__ void gat_gather(const int* __restrict__ base, const int2* __restrict__ rec,
                           const float* __restrict__ u, const float* __restrict__ vv,
                           const bf16* __restrict__ h, const float* __restrict__ bias,
                           float* __restrict__ xout, float* __restrict__ pool,
                           const int* __restrict__ batch, int n) {
  int wid = threadIdx.x >> 6, lane = threadIdx.x & 63;
  int node = blockIdx.x * 4 + wid;
  if (node >= n) return;
  int s0 = base[node], s1 = base[node + 1];
  float vt = vv[node];
  float m = -3.4e38f;
  for (int p = s0 + lane; p < s1; p += 64) {
    float lg = u[rec[p].x] + vt; lg = lg >= 0.f ? lg : 0.2f * lg;
    m = fmaxf(m, lg);
  }
#pragma unroll
  for (int s = 32; s; s >>= 1) m = fmaxf(m, __shfl_xor(m, s));
  float ssum = 0.f;
  for (int p = s0 + lane; p < s1; p += 64) {
    float lg = u[rec[p].x] + vt; lg = lg >= 0.f ? lg : 0.2f * lg;
    ssum += __expf(lg - m);
  }
#pragma unroll
  for (int s = 32; s; s >>= 1) ssum += __shfl_xor(ssum, s);
  float rs = 1.f / ssum;
  int d0 = lane * 2;
  float a0 = 0.f, a1 = 0.f;
  for (int p = s0; p < s1; p++) {
    int2 r = rec[p];
    float lg = u[r.x] + vt; lg = lg >= 0.f ? lg : 0.2f * lg;
    float alpha = __expf(lg - m) * rs;
    __hip_bfloat162 hv = *(const __hip_bfloat162*)&h[(size_t)r.x * 128 + d0];
    a0 = fmaf(__bfloat162float(hv.x), alpha, a0);
    a1 = fmaf(__bfloat162float(hv.y), alpha, a1);
  }
  float v0 = fmaxf(a0 + bias[d0], 0.f);
  float v1 = fmaxf(a1 + bias[d0 + 1], 0.f);
  if (xout) *(float2*)&xout[(size_t)node * 128 + d0] = make_float2(v0, v1);
  int g = batch[node];
  atomicAdd(&pool[(size_t)g * 128 + d0], v0);
  atomicAdd(&pool[(size_t)g * 128 + d0 + 1], v1);
}

// ---------------------------------------------------------------- fused drug MLP
// h1=relu(x1@w1+b1); hd2=relu(h1@w2+b2); x=hd2@w3+b3+0.2*vn  -> bf16
__global__ void mlp_drug(const float* __restrict__ x1, const float* __restrict__ w1,
                         const float* __restrict__ b1, const float* __restrict__ w2,
                         const float* __restrict__ b2, const float* __restrict__ w3,
                         const float* __restrict__ b3, const float* __restrict__ vn,
                         bf16* __restrict__ xout, int n) {
  __shared__ float l1[4][128];
  __shared__ float l2[4][64];
  int wid = threadIdx.x >> 6, lane = threadIdx.x & 63;
  int node = blockIdx.x * 4 + wid;
  const float* xr = x1 + (size_t)node * 52;
  int d0 = lane * 2;
  float a0 = b1[d0], a1 = b1[d0 + 1];
  for (int k = 0; k < 52; k++) {
    float xk = xr[k];
    a0 = fmaf(xk, w1[k * 128 + d0], a0); a1 = fmaf(xk, w1[k * 128 + d0 + 1], a1);
  }
  l1[wid][d0] = fmaxf(a0, 0.f); l1[wid][d0 + 1] = fmaxf(a1, 0.f);
  __syncthreads();
  float h2 = b2[lane];
  for (int k = 0; k < 128; k++) h2 = fmaf(l1[wid][k], w2[k * 64 + lane], h2);
  l2[wid][lane] = fmaxf(h2, 0.f);
  __syncthreads();
  float o0 = b3[d0] + 0.2f * vn[d0], o1 = b3[d0 + 1] + 0.2f * vn[d0 + 1];
  for (int k = 0; k < 64; k++) {
    float hk = l2[wid][k];
    o0 = fmaf(hk, w3[k * 128 + d0], o0); o1 = fmaf(hk, w3[k * 128 + d0 + 1], o1);
  }
  __hip_bfloat162 pr; pr.x = __float2bfloat16(o0); pr.y = __float2bfloat16(o1);
  *(__hip_bfloat162*)&xout[(size_t)node * 128 + d0] = pr;
}

// ---------------------------------------------------------------- elementwise
__global__ void cnt_kernel(const int* __restrict__ batch, float* __restrict__ cnt, int n) {
  int i = blockIdx.x * blockDim.x + threadIdx.x;
  if (i < n) atomicAdd(&cnt[batch[i]], 1.0f);
}

// t = pool_drug + vn  (pool_drug == segment_sum(x11) after GAT layer 0)
__global__ void tvn_k(const float* __restrict__ pool, const float* __restrict__ vn,
                      float* __restrict__ t, int n) {
  int i = blockIdx.x * blockDim.x + threadIdx.x;
  if (i < n) t[i] = pool[i] + vn[i & 127];
}

// xbf2 = bf16(x11 + 0.2*drugv[batch]); 2 dims per thread
__global__ void add_cast(const float* __restrict__ x11, const float* __restrict__ dr,
                         const int* __restrict__ batch, bf16* __restrict__ out, int n2) {
  int i = blockIdx.x * blockDim.x + threadIdx.x;
  if (i >= n2) return;
  int node = i >> 6, d0 = (i & 63) << 1;
  const float* drb = dr + (size_t)batch[node] * 128 + d0;
  float2 xv = *(const float2*)&x11[(size_t)node * 128 + d0];
  __hip_bfloat162 pr;
  pr.x = __float2bfloat16(xv.x + 0.2f * drb[0]);
  pr.y = __float2bfloat16(xv.y + 0.2f * drb[1]);
  *(__hip_bfloat162*)&out[(size_t)node * 128 + d0] = pr;
}

// ---------------------------------------------------------------- fused head
// per block: 8 rows; z(256)->h2(512,raw to out)->relu->z3(256)->z4(128)->out(1)
__global__ __launch_bounds__(256) void head_fused(
    const float* __restrict__ pool_d, const float* __restrict__ cnt_d,
    const float* __restrict__ pool_a, const float* __restrict__ cnt_a,
    const float* __restrict__ fc1_w, const float* __restrict__ fc1_b,
    const float* __restrict__ fc2_w, const float* __restrict__ fc2_b,
    const float* __restrict__ fc3_w, const float* __restrict__ fc3_b,
    const float* __restrict__ ow, const float* __restrict__ ob,
    float* __restrict__ out, float* __restrict__ h2out) {
  __shared__ float z[8][256], h2[8][512], z3[8][256], z4[8][128];
  int tid = threadIdx.x; int r0 = blockIdx.x * 8;
  for (int idx = tid; idx < 8 * 256; idx += 256) {
    int r = idx >> 8, d = idx & 255; int b = r0 + r;
    z[r][d] = d < 128 ? pool_d[b * 128 + d] / fmaxf(cnt_d[b], 1.f)
                      : pool_a[b * 128 + d - 128] / fmaxf(cnt_a[b], 1.f);
  }
  __syncthreads();
  for (int idx = tid; idx < 8 * 512; idx += 256) {
    int r = idx >> 9, n = idx & 511;
    float acc = fc1_b[n];
    for (int k = 0; k < 256; k++) acc = fmaf(z[r][k], fc1_w[k * 512 + n], acc);
    h2out[(size_t)(r0 + r) * 512 + n] = acc;
    h2[r][n] = fmaxf(acc, 0.f);
  }
  __syncthreads();
  for (int idx = tid; idx < 8 * 256; idx += 256) {
    int r = idx >> 8, n = idx & 255;
    float acc = fc2_b[n];
    for (int k = 0; k < 512; k++) acc = fmaf(h2[r][k], fc2_w[k * 256 + n], acc);
    z3[r][n] = fmaxf(acc, 0.f);
  }
  __syncthreads();
  for (int idx = tid; idx < 8 * 128; idx += 256) {
    int r = idx >> 7, n = idx & 127;
    float acc = fc3_b[n];
    for (int k = 0; k < 256; k++) acc = fmaf(z3[r][k], fc3_w[k * 128 + n], acc);
    z4[r][n] = fmaxf(acc, 0.f);
  }
  __syncthreads();
  if (tid < 8 * 16) {
    int r = tid >> 4, l = tid & 15;
    float acc = 0.f;
    for (int k = l; k < 128; k += 16) acc = fmaf(z4[r][k], ow[k], acc);
#pragma unroll
    for (int s = 8; s; s >>= 1) acc += __shfl_down(acc, s);
    if (l == 0) out[r0 + r] = acc + ob[0];
  }
}

// ---------------------------------------------------------------- launch
static inline int cdiv(int a, int b) { return (a + b - 1) / b; }

extern "C" void kernel_launch(void* const* d_in, const int* in_sizes, int n_in,
                              void* d_out, int out_size, void* d_ws, size_t ws_size,
                              hipStream_t stream)
{
  const float* x1      = (const float*)d_in[0];
  const float* x3      = (const float*)d_in[1];
  const float* ami_dis = (const float*)d_in[2];
  const float* ami_li  = (const float*)d_in[3];
  const float* fc00_w = (const float*)d_in[4];  const float* fc00_b = (const float*)d_in[5];
  const float* fc01_w = (const float*)d_in[6];  const float* fc01_b = (const float*)d_in[7];
  const float* fc02_w = (const float*)d_in[8];  const float* fc02_b = (const float*)d_in[9];
  const float* w1 = (const float*)d_in[10];     const float* b1 = (const float*)d_in[11];
  const float* w2 = (const float*)d_in[12];     const float* b2 = (const float*)d_in[13];
  const float* fc03_w = (const float*)d_in[14]; const float* fc03_b = (const float*)d_in[15];
  const float* gat_W  = (const float*)d_in[16]; const float* gat_as = (const float*)d_in[17];
  const float* gat_ad = (const float*)d_in[18]; const float* gat_bias = (const float*)d_in[19];
  const float* vn_emb = (const float*)d_in[20];
  const float* vl1_w = (const float*)d_in[21];  const float* vl1_b = (const float*)d_in[22];
  const float* bn1_g = (const float*)d_in[23];  const float* bn1_b = (const float*)d_in[24];
  const float* bn1_m = (const float*)d_in[25];  const float* bn1_v = (const float*)d_in[26];
  const float* vl2_w = (const float*)d_in[27];  const float* vl2_b = (const float*)d_in[28];
  const float* bn2_g = (const float*)d_in[29];  const float* bn2_b = (const float*)d_in[30];
  const float* bn2_m = (const float*)d_in[31];  const float* bn2_v = (const float*)d_in[32];
  const float* gcn_W = (const float*)d_in[33];  const float* gcn_b = (const float*)d_in[34];
  const float* fc1_w = (const float*)d_in[35];  const float* fc1_b = (const float*)d_in[36];
  const float* fc2_w = (const float*)d_in[37];  const float* fc2_b = (const float*)d_in[38];
  const float* fc3_w = (const float*)d_in[39];  const float* fc3_b = (const float*)d_in[40];
  const float* out_w = (const float*)d_in[41];  const float* out_b = (const float*)d_in[42];
  const int* drug_ei   = (const int*)d_in[43];
  const int* ami_ei    = (const int*)d_in[44];
  const int* batch1    = (const int*)d_in[45];
  const int* ami_batch = (const int*)d_in[46];

  char* ws = (char*)d_ws;
  // ---- small persistent arena
  bf16*  Bt0   = (bf16*)(ws + 0);          // 1024x1920
  bf16*  Bt1   = (bf16*)(ws + 3932160);    // 512x1024
  bf16*  Bt2   = (bf16*)(ws + 4980736);    // 128x512 (row127=0)
  bf16*  BtGCN = (bf16*)(ws + 5111808);    // 3x128x128
  bf16*  BtGAT = (bf16*)(ws + 5210112);    // 3x128x128
  float* deg   = (float*)(ws + 5308416);   // ---- zero block start
  float* dinv  = (float*)(ws + 5410816);
  float* pool_ami  = (float*)(ws + 5513216);
  float* pool_drug = (float*)(ws + 5644288);
  float* cnt_ami   = (float*)(ws + 5775360);
  float* cnt_drug  = (float*)(ws + 5776384); // ---- zero block end @5777408
  float* uarr  = (float*)(ws + 6039552);
  float* varr  = (float*)(ws + 6080512);
  int*   bsum3 = (int*)  (ws + 6121472);   // 32 ints
  int*   bsum1 = (int*)  (ws + 6121728);   // 32 ints
  float* tbuf  = (float*)(ws + 6572032);   // 256x128
  float* t2buf = (float*)(ws + 6703104);   // 256x256
  float* drugv = (float*)(ws + 6965248);   // 256x128

  // ---- arena A (98.3 MB, aliased across phases)
  const size_t AA = 8388608;
  bf16*  A3bf = (bf16*)(ws + AA);                    // 25600x1920 (dead after fc00)
  bf16*  a2bf = (bf16*)(ws + AA);                    // 25600x512  (after fc01)
  bf16*  abf  = (bf16*)(ws + AA + 41943040);         // 25600x128 bf16 activation
  bf16*  ybf  = (bf16*)(ws + AA + 52428800);         // 25600x128 bf16 gathered
  // CSR (region dead after fc00 reads A3bf)
  int*  base3 = (int*) (ws + AA + 68157440);         // 25601 ints
  int*  cur3  = (int*) (ws + AA + 68812800);         // 25600 ints
  int2* rec3  = (int2*)(ws + AA + 69206016);         // 844800 x 8B
  int*  base1 = (int*) (ws + AA + 77594624);         // 10241 ints
  int*  cur1  = (int*) (ws + AA + 78118912);         // 10240 ints
  int2* rec1  = (int2*)(ws + AA + 78643200);         // 92160 x 8B
  // drug phase (ami bufs dead; CSR1 still live at +77.5MB)
  bf16*  xbf   = (bf16*) (ws + AA + 0);              // 10240x128 bf16
  bf16*  hgat  = (bf16*) (ws + AA + 5242880);        // 10240x128 bf16
  float* x11   = (float*)(ws + AA + 10485760);       // 10240x128 f32
  bf16*  xbf2  = (bf16*) (ws + AA + 15728640);       // 10240x128 bf16
  // ---- arena B
  const size_t ABo = AA + 98304000;
  bf16*  a1bf = (bf16*)(ws + ABo);                   // 25600x1024 (total ~159.1 MB)

  const int Etot3 = EE3 + NN3, Etot1 = EE1 + NN1;

  // ================= prep: weight transposes + x3 cast =================
  {
    dim3 b(32, 8);
    transpose_cast_bf<<<dim3(60, 32), b, 0, stream>>>(fc00_w, Bt0, 1900, 1024, 1920, 1024);
    transpose_cast_bf<<<dim3(32, 16), b, 0, stream>>>(fc01_w, Bt1, 1024, 512, 1024, 512);
    transpose_cast_bf<<<dim3(16, 4), b, 0, stream>>>(fc02_w, Bt2, 512, 127, 512, 128);
    transpose_cast_bf<<<dim3(4, 4, 3), b, 0, stream>>>(gcn_W, BtGCN, 128, 128, 128, 128);
    transpose_cast_bf<<<dim3(4, 4, 3), b, 0, stream>>>(gat_W, BtGAT, 128, 128, 128, 128);
  }
  cast_pad8<<<cdiv(25600 * 240, 256), 256, 0, stream>>>(x3, A3bf, 25600, 1900, 1920);

  // zero: deg, dinv, pools, cnts (contiguous)
  hipMemsetAsync(deg, 0, 468992, stream);

  // ================= ami branch: MLP (bf16 MFMA) =================
  gemm_mfma<1, 0, 0, 0><<<200 * 8, 256, 0, stream>>>(A3bf, Bt0, fc00_b, a1bf, nullptr, nullptr, nullptr, 25600, 1024, 1920);
  // A3bf dead -> CSR arena usable from here
  gemm_mfma<1, 0, 0, 0><<<200 * 4, 256, 0, stream>>>(a1bf, Bt1, fc01_b, a2bf, nullptr, nullptr, nullptr, 25600, 512, 1024);
  gemm_mfma<1, 0, 1, 0><<<200 * 1, 256, 0, stream>>>(a2bf, Bt2, fc02_b, abf, ami_li, nullptr, nullptr, 25600, 128, 512);

  // ================= graph prep =================
  deg_kernel<<<cdiv(EE3, 256), 256, 0, stream>>>(ami_ei + EE3, ami_dis, deg, EE3);
  dinv_kernel<<<cdiv(NN3, 256), 256, 0, stream>>>(deg, dinv, NN3);
  cnt_kernel<<<cdiv(NN3, 256), 256, 0, stream>>>(ami_batch, cnt_ami, NN3);
  cnt_kernel<<<cdiv(NN1, 256), 256, 0, stream>>>(batch1, cnt_drug, NN1);

  // GCN CSR
  hipMemsetAsync(cur3, 0, 102400, stream);
  hist_csr<<<cdiv(Etot3, 256), 256, 0, stream>>>(ami_ei + EE3, EE3, Etot3, cur3);
  scan_blocks<<<25, 1024, 0, stream>>>(cur3, base3, bsum3, NN3);
  scan_tops<<<1, 64, 0, stream>>>(bsum3, base3, NN3, 25);
  scan_add<<<25, 1024, 0, stream>>>(base3, bsum3, cur3, NN3);
  fill_csr<<<cdiv(Etot3, 256), 256, 0, stream>>>(ami_ei, ami_ei + EE3, ami_dis, dinv,
                                                 base3, cur3, rec3, EE3, Etot3);
  // GAT CSR
  hipMemsetAsync(cur1, 0, 40960, stream);
  hist_csr<<<cdiv(Etot1, 256), 256, 0, stream>>>(drug_ei + EE1, EE1, Etot1, cur1);
  scan_blocks<<<10, 1024, 0, stream>>>(cur1, base1, bsum1, NN1);
  scan_tops<<<1, 64, 0, stream>>>(bsum1, base1, NN1, 10);
  scan_add<<<10, 1024, 0, stream>>>(base1, bsum1, cur1, NN1);
  fill_csr<<<cdiv(Etot1, 256), 256, 0, stream>>>(drug_ei, drug_ei + EE1, nullptr, nullptr,
                                                 base1, cur1, rec1, EE1, Etot1);

  // ================= 3x GCN: Y = A_hat@X (bf16), then X' = relu(Y@W+b) + pool ===
  for (int l = 0; l < 3; l++) {
    gather_pre<<<cdiv(NN3, 4), 256, 0, stream>>>(base3, rec3, abf, ybf, NN3);
    gemm_mfma<1, 0, 0, 1><<<200, 256, 0, stream>>>(ybf, BtGCN + l * 16384, gcn_b + l * 128,
                                                   abf, nullptr, pool_ami, ami_batch, NN3, 128, 128);
  }

  // ================= drug branch: fused MLP -> xbf (bf16) =================
  mlp_drug<<<NN1 / 4, 256, 0, stream>>>(x1, w1, b1, w2, b2, fc03_w, fc03_b, vn_emb, xbf, NN1);

  // ================= GAT layer 0 =================
  gemm_mfma<0, 0, 0, 0><<<80, 256, 0, stream>>>(xbf, BtGAT, nullptr, hgat, nullptr, nullptr, nullptr, NN1, 128, 128);
  gat_uv<<<cdiv(NN1, 4), 256, 0, stream>>>(hgat, gat_as, gat_ad, uarr, varr, NN1);
  gat_gather<<<cdiv(NN1, 4), 256, 0, stream>>>(base1, rec1, uarr, varr, hgat, gat_bias,
                                               x11, pool_drug, batch1, NN1);

  // ================= virtual-node update (t = pool_drug + vn) =================
  tvn_k<<<cdiv(BB * 128, 256), 256, 0, stream>>>(pool_drug, vn_emb, tbuf, BB * 128);
  gemm_simt<1, 1><<<cdiv(BB * 256, 256), 256, 0, stream>>>(tbuf, vl1_w, vl1_b, bn1_g, bn1_b, bn1_m, bn1_v, t2buf, BB, 256, 128);
  gemm_simt<1, 1><<<cdiv(BB * 128, 256), 256, 0, stream>>>(t2buf, vl2_w, vl2_b, bn2_g, bn2_b, bn2_m, bn2_v, drugv, BB, 128, 256);
  add_cast<<<cdiv(NN1 * 64, 256), 256, 0, stream>>>(x11, drugv, batch1, xbf2, NN1 * 64);

  // ================= GAT layers 1,2 =================
  for (int l = 1; l < 3; l++) {
    gemm_mfma<0, 0, 0, 0><<<80, 256, 0, stream>>>(xbf2, BtGAT + l * 16384, nullptr, hgat, nullptr, nullptr, nullptr, NN1, 128, 128);
    gat_uv<<<cdiv(NN1, 4), 256, 0, stream>>>(hgat, gat_as + l * 128, gat_ad + l * 128, uarr, varr, NN1);
    gat_gather<<<cdiv(NN1, 4), 256, 0, stream>>>(base1, rec1, uarr, varr, hgat, gat_bias + l * 128,
                                                 nullptr, pool_drug, batch1, NN1);
  }

  // ================= fused head (means + 4 GEMMs + out) =================
  head_fused<<<32, 256, 0, stream>>>(pool_drug, cnt_drug, pool_ami, cnt_ami,
                                     fc1_w, fc1_b, fc2_w, fc2_b, fc3_w, fc3_b,
                                     out_w, out_b, (float*)d_out, (float*)d_out + 256);
}